// Round 16
// baseline (183.143 us; speedup 1.0000x reference)
//
#include <hip/hip_runtime.h>
#include <hip/hip_bf16.h>
#include <math.h>

#define B_ 2
#define S_ 2048
#define E_ 768
#define H_ 12
#define D_ 64
#define M_TOT (B_*S_)   // 4096

typedef __attribute__((ext_vector_type(8))) short s16x8;
typedef __attribute__((ext_vector_type(4))) float f32x4;

__device__ __forceinline__ unsigned short f2bf(float f) {
  union { float f; unsigned u; } v; v.f = f;
  unsigned r = (v.u + 0x7fffu + ((v.u >> 16) & 1u)) >> 16;
  return (unsigned short)r;
}

__device__ __forceinline__ unsigned pkbf(float a, float b) {
  __hip_bfloat162 h = __float22bfloat162_rn(make_float2(a, b));
  unsigned u;
  __builtin_memcpy(&u, &h, 4);
  return u;
}

__device__ __forceinline__ float bf2f(unsigned short u) {
  union { unsigned u; float f; } v; v.u = (unsigned)u << 16;
  return v.f;
}

__device__ __forceinline__ int swz(int r) { return ((r >> 3) ^ r) & 7; }

__device__ __forceinline__ void gload_lds16(const unsigned short* g, unsigned short* l) {
  __builtin_amdgcn_global_load_lds(
      (const __attribute__((address_space(1))) void*)g,
      (__attribute__((address_space(3))) void*)l, 16, 0, 0);
}

// ---------------- transpose+convert block: in [R][C] f32 -> out [C][R] bf16
__device__ __forceinline__ void tconv_block(const float* __restrict__ in,
                                            unsigned short* __restrict__ out,
                                            int R, int C, int bx, int by, int t,
                                            float (*tile)[33]) {
  int c0 = bx * 32, r0 = by * 32;
  int cl = t & 31, rl = t >> 5;
  #pragma unroll
  for (int p = 0; p < 4; ++p)
    tile[rl + p*8][cl] = in[(size_t)(r0 + rl + p*8)*C + c0 + cl];
  __syncthreads();
  int rl2 = t & 31, cl2 = t >> 5;
  #pragma unroll
  for (int p = 0; p < 4; ++p)
    out[(size_t)(c0 + cl2 + p*8)*R + r0 + rl2] = f2bf(tile[rl2][cl2 + p*8]);
}

// ---------------- layernorm one row (wave of 64 lanes, no barriers)
__device__ __forceinline__ void ln_row(const float* __restrict__ xr,
                                       const float* __restrict__ g,
                                       const float* __restrict__ b,
                                       unsigned short* __restrict__ orow, int lane) {
  float4 v[3];
  float s = 0.f, sq = 0.f;
  #pragma unroll
  for (int p = 0; p < 3; ++p) {
    v[p] = *reinterpret_cast<const float4*>(xr + p*256 + lane*4);
    s  += v[p].x + v[p].y + v[p].z + v[p].w;
    sq += v[p].x*v[p].x + v[p].y*v[p].y + v[p].z*v[p].z + v[p].w*v[p].w;
  }
  #pragma unroll
  for (int off = 32; off; off >>= 1) {
    s  += __shfl_xor(s,  off, 64);
    sq += __shfl_xor(sq, off, 64);
  }
  float mu  = s * (1.f/E_);
  float var = sq * (1.f/E_) - mu*mu;
  float rstd = rsqrtf(var + 1e-5f);
  #pragma unroll
  for (int p = 0; p < 3; ++p) {
    int c = p*256 + lane*4;
    float4 gg = *reinterpret_cast<const float4*>(g + c);
    float4 bb = *reinterpret_cast<const float4*>(b + c);
    ushort4 o;
    o.x = f2bf((v[p].x-mu)*rstd*gg.x + bb.x);
    o.y = f2bf((v[p].y-mu)*rstd*gg.y + bb.y);
    o.z = f2bf((v[p].z-mu)*rstd*gg.z + bb.z);
    o.w = f2bf((v[p].w-mu)*rstd*gg.w + bb.w);
    *reinterpret_cast<ushort4*>(orow + c) = o;
  }
}

// ---------------- mega-prep: 4 weight tconvs + LN1, one kernel (flat decode)
__global__ __launch_bounds__(256) void prep_kernel(
    const float* __restrict__ w_attn,  unsigned short* __restrict__ wt_attn,
    const float* __restrict__ w_aproj, unsigned short* __restrict__ wt_aproj,
    const float* __restrict__ w_fc,    unsigned short* __restrict__ wt_fc,
    const float* __restrict__ w_fproj, unsigned short* __restrict__ wt_fproj,
    const float* __restrict__ x, const float* __restrict__ ln1g,
    const float* __restrict__ ln1b, unsigned short* __restrict__ h1) {
  __shared__ float tile[32][33];
  int id = blockIdx.x, t = threadIdx.x;
  if (id < 1728) {
    tconv_block(w_attn, wt_attn, 768, 2304, id % 72, id / 72, t, tile);
  } else if (id < 2304) {
    int r = id - 1728; tconv_block(w_aproj, wt_aproj, 768, 768, r % 24, r / 24, t, tile);
  } else if (id < 4608) {
    int r = id - 2304; tconv_block(w_fc, wt_fc, 768, 3072, r % 96, r / 96, t, tile);
  } else if (id < 6912) {
    int r = id - 4608; tconv_block(w_fproj, wt_fproj, 3072, 768, r % 24, r / 24, t, tile);
  } else {
    int row = (id - 6912) * 4 + (t >> 6);
    ln_row(x + (size_t)row * E_, ln1g, ln1b, h1 + (size_t)row * E_, t & 63);
  }
}

// ---------------- layernorm (4 rows/block): x f32 [rows][768] -> out bf16
__global__ __launch_bounds__(256) void ln_kernel(const float* __restrict__ x,
                                                 const float* __restrict__ g,
                                                 const float* __restrict__ b,
                                                 unsigned short* __restrict__ out) {
  int row = blockIdx.x * 4 + (threadIdx.x >> 6);
  ln_row(x + (size_t)row * E_, g, b, out + (size_t)row * E_, threadIdx.x & 63);
}

// ---------------- V transpose: qkv bf16 [B*S][2304] -> vt [ (b*H+h)*64+d ][ S ] bf16
__global__ __launch_bounds__(256) void vtrans_kernel(const unsigned short* __restrict__ qkv,
                                                     unsigned short* __restrict__ vt) {
  __shared__ unsigned short tile[32][33];
  int s0 = blockIdx.x * 32;
  int by = blockIdx.y;                // bh*2 + d-half
  int bh = by >> 1, dh = by & 1;
  int b = bh / H_, h = bh % H_;
  int t = threadIdx.x;
  const unsigned short* src = qkv + (size_t)(b*S_)*2304 + 2*E_ + h*64 + dh*32;
  int srow = t >> 3, dq = t & 7;      // load: 32 s-rows x 32 d
  ushort4 v = *reinterpret_cast<const ushort4*>(src + (size_t)(s0 + srow)*2304 + dq*4);
  tile[srow][dq*4+0] = v.x; tile[srow][dq*4+1] = v.y;
  tile[srow][dq*4+2] = v.z; tile[srow][dq*4+3] = v.w;
  __syncthreads();
  int drow = t >> 3, sq = t & 7;      // store: 32 d-rows x 32 s
  ushort4 o;
  o.x = tile[sq*4+0][drow]; o.y = tile[sq*4+1][drow];
  o.z = tile[sq*4+2][drow]; o.w = tile[sq*4+3][drow];
  *reinterpret_cast<ushort4*>(vt + (size_t)(bh*64 + dh*32 + drow)*S_ + s0 + sq*4) = o;
}

// ---------------- GEMM v6: BK=128, BM=64, BN=128, single-buffered LDS,
// XCD-aware block remap: each XCD owns a contiguous m-chunk, n-fastest within.
// MODE 0: store bf16 ; MODE 1: store f32 + residual ; MODE 2: gelu -> bf16
template<int MODE, int BM>
__global__ __launch_bounds__(256) void gemm_kernel(
    const unsigned short* __restrict__ A,
    const unsigned short* __restrict__ Wt,
    const float* __restrict__ bias,
    const float* __restrict__ res,
    unsigned short* __restrict__ outb,
    float* __restrict__ outf,
    int M, int N, int K)
{
  constexpr int Mi = BM / 32;
  constexpr int Ni = 4;
  __shared__ __align__(16) unsigned short As[BM*128];
  __shared__ __align__(16) unsigned short Ws[128*128];

  int gx = gridDim.x, gy = gridDim.y;
  int bid = blockIdx.y * gx + blockIdx.x;
  int xcd = bid & 7, loc = bid >> 3;
  int m = xcd * (gy >> 3) + loc / gx;
  int n = loc % gx;
  int n0 = n * 128, m0 = m * BM;

  int t = threadIdx.x, lane = t & 63, w = t >> 6;
  f32x4 acc[Mi][Ni] = {};
  int KT = K >> 7;

  auto stage = [&](int kt) {
    int k0 = kt << 7;
    #pragma unroll
    for (int p = 0; p < BM/16; ++p) {
      int off = p*2048 + w*512 + lane*8;
      int r = off >> 7;
      int slot = (off & 127) >> 3;
      int k8 = slot ^ swz(r);
      gload_lds16(A + (size_t)(m0 + r)*K + k0 + k8*8, As + p*2048 + w*512);
    }
    #pragma unroll
    for (int p = 0; p < 8; ++p) {
      int off = p*2048 + w*512 + lane*8;
      int r = off >> 7;
      int slot = (off & 127) >> 3;
      int k8 = slot ^ swz(r);
      gload_lds16(Wt + (size_t)(n0 + r)*K + k0 + k8*8, Ws + p*2048 + w*512);
    }
  };

  int wm = (w >> 1) * (BM/2), wn = (w & 1) * 64;
  int li = lane & 15, g = lane >> 4;

  int aoff[Mi], boff[Ni];
  #pragma unroll
  for (int mi = 0; mi < Mi; ++mi) {
    int r = wm + mi*16 + li;
    aoff[mi] = r*128 + ((g ^ swz(r)) << 3);
  }
  #pragma unroll
  for (int ni = 0; ni < Ni; ++ni) {
    int r = wn + ni*16 + li;
    boff[ni] = r*128 + ((g ^ swz(r)) << 3);
  }

  stage(0);
  for (int kt = 0; kt < KT; ++kt) {
    __syncthreads();
    #pragma unroll
    for (int kk = 0; kk < 4; ++kk) {
      int kx = kk << 5;
      s16x8 af[Mi], bf[Ni];
      #pragma unroll
      for (int mi = 0; mi < Mi; ++mi)
        af[mi] = *reinterpret_cast<const s16x8*>(As + (aoff[mi] ^ kx));
      #pragma unroll
      for (int ni = 0; ni < Ni; ++ni)
        bf[ni] = *reinterpret_cast<const s16x8*>(Ws + (boff[ni] ^ kx));
      #pragma unroll
      for (int mi = 0; mi < Mi; ++mi)
        #pragma unroll
        for (int ni = 0; ni < Ni; ++ni)
          acc[mi][ni] = __builtin_amdgcn_mfma_f32_16x16x32_bf16(af[mi], bf[ni], acc[mi][ni], 0, 0, 0);
    }
    __syncthreads();
    if (kt + 1 < KT) stage(kt + 1);
  }

  #pragma unroll
  for (int mi = 0; mi < Mi; ++mi) {
    #pragma unroll
    for (int j = 0; j < 4; ++j) {
      int row = m0 + wm + mi*16 + g*4 + j;
      #pragma unroll
      for (int ni = 0; ni < Ni; ++ni) {
        int col = n0 + wn + ni*16 + li;
        float v = acc[mi][ni][j] + bias[col];
        size_t idx = (size_t)row * N + col;
        if (MODE == 0) {
          outb[idx] = f2bf(v);
        } else if (MODE == 1) {
          outf[idx] = v + res[idx];
        } else {
          float gv = 0.5f * v * (1.f + erff(v * 0.70710678118f));
          outb[idx] = f2bf(gv);
        }
      }
    }
  }
}

// ---------------- causal flash attention v11: v10 + bh-per-XCD remap + exp2
// (Q pre-scaled by log2(e); all m/l in log2-domain; merge uses exp2f).
// Block = (bh, qtile of 64 rows, kv chunk of <=512). 4 waves, wave owns 16 q rows.
// Partial slot (floats, stride 2176): o bf16[64][64] @0, m[64] @2048, l[64] @2112.
__global__ __launch_bounds__(256) void attn_kernel(const unsigned short* __restrict__ qkv,
                                                   const unsigned short* __restrict__ vtg,
                                                   unsigned short* __restrict__ out,
                                                   float* __restrict__ part) {
  __shared__ __align__(16) unsigned short Ks[2][64*64];   // [kv][d] swizzled
  __shared__ __align__(16) unsigned short Vs[2][64*64];   // [d][kv] swizzled
  __shared__ __align__(16) unsigned short Pl[4][16*64];   // per-wave P [16q][64k] swizzled

  // ---- XCD-aware decode: grid 1920 = 8 xcd x 240; each XCD owns 3 bh
  // (3 heads' K/V = ~3MB, fits 4MB private L2 -> K/V fetched ~once chip-wide)
  int gid = blockIdx.x;
  int xcd = gid & 7, loc = gid >> 3;           // loc in [0,240)
  int bh = xcd * 3 + loc / 80, zi = loc % 80;
  int qt, ch;
  if (zi < 8)       { qt = zi;                ch = 0; }
  else if (zi < 24) { qt = 8  + ((zi-8)>>1);  ch = (zi-8) & 1; }
  else if (zi < 48) { qt = 16 + (zi-24)/3;    ch = (zi-24) % 3; }
  else              { qt = 24 + ((zi-48)>>2); ch = (zi-48) & 3; }
  int nc = (qt + 8) >> 3;                      // ceil((qt+1)/8)
  int b = bh / H_, h = bh % H_;
  int t = threadIdx.x, lane = t & 63, w = t >> 6;
  int li = lane & 15, g = lane >> 4;
  const size_t rs = 3*E_;                      // 2304
  const unsigned short* base  = qkv + (size_t)b * S_ * rs;
  const unsigned short* kbase = base + E_ + h*64;
  const unsigned short* vbase = vtg + (size_t)bh * 64 * S_;   // rows d, cols s

  int q0w = qt*64 + w*16;                      // this wave's 16 q rows
  int qmin = q0w;
  s16x8 qf[2];
  #pragma unroll
  for (int f = 0; f < 2; ++f)
    qf[f] = *reinterpret_cast<const s16x8*>(base + (size_t)(q0w + li)*rs + h*64 + f*32 + g*8);
  // pre-scale Q by log2(e): scores come out of MFMA already in log2 domain
  #pragma unroll
  for (int f = 0; f < 2; ++f)
    #pragma unroll
    for (int i = 0; i < 8; ++i)
      qf[f][i] = (short)f2bf(bf2f((unsigned short)qf[f][i]) * 1.44269504f);

  // ---- hoisted LDS offsets (loop-invariant)
  int koff0[4], koff1[4], poff[4], prd[2], voff[2][4];
  #pragma unroll
  for (int nh = 0; nh < 4; ++nh) {
    int r = nh*16 + li, sw_ = r & 7;
    koff0[nh] = r*64 + ((g ^ sw_) << 3);
    koff1[nh] = r*64 + (((4 + g) ^ sw_) << 3);
    poff[nh]  = li*64 + (((2*nh + (g >> 1)) ^ (li & 7)) << 3) + (g & 1)*4;
  }
  #pragma unroll
  for (int kk = 0; kk < 2; ++kk) {
    prd[kk] = li*64 + (((kk*4 + g) ^ (li & 7)) << 3);
    #pragma unroll
    for (int n2 = 0; n2 < 4; ++n2) {
      int r = n2*16 + li;
      voff[kk][n2] = r*64 + (((kk*4 + g) ^ (r & 7)) << 3);
    }
  }

  float mrun = -1e30f, lrun = 0.f;
  f32x4 o[4] = {};

  auto stage = [&](int kvt, int buf) {
    int kv0 = kvt * 64;
    #pragma unroll
    for (int p = 0; p < 2; ++p) {
      int off = p*2048 + w*512 + lane*8;
      int r = off >> 6;
      int slot = (off & 63) >> 3;
      gload_lds16(kbase + (size_t)(kv0 + r)*rs + ((slot ^ (r & 7)) << 3),
                  &Ks[buf][p*2048 + w*512]);
      gload_lds16(vbase + (size_t)r*S_ + kv0 + ((slot ^ (r & 7)) << 3),
                  &Vs[buf][p*2048 + w*512]);
    }
  };

  int t0 = (ch * 512) >> 6;
  int t1 = min((ch + 1) * 512, (qt + 1) * 64) >> 6;   // exclusive tile bound

  stage(t0, 0);
  __syncthreads();

  for (int kt = t0; kt < t1; ++kt) {
    int cur = (kt - t0) & 1;
    if (kt + 1 < t1) stage(kt + 1, cur ^ 1);   // async prefetch overlaps compute
    int kv0 = kt * 64;
    unsigned short* Pw = Pl[w];

    if (kv0 <= qmin + 15) {
      // ---- swapped QK^T (log2-domain scores)
      f32x4 pm[4];
      __builtin_amdgcn_s_setprio(1);
      #pragma unroll
      for (int nh = 0; nh < 4; ++nh) {
        s16x8 kf0 = *reinterpret_cast<const s16x8*>(&Ks[cur][koff0[nh]]);
        s16x8 kf1 = *reinterpret_cast<const s16x8*>(&Ks[cur][koff1[nh]]);
        f32x4 z = {};
        z = __builtin_amdgcn_mfma_f32_16x16x32_bf16(kf0, qf[0], z, 0, 0, 0);
        z = __builtin_amdgcn_mfma_f32_16x16x32_bf16(kf1, qf[1], z, 0, 0, 0);
        pm[nh] = z;
      }
      __builtin_amdgcn_s_setprio(0);

      // ---- causal mask (diagonal-straddling tiles only)
      if (kv0 + 63 > qmin) {
        int q = qmin + li;
        #pragma unroll
        for (int nh = 0; nh < 4; ++nh)
          #pragma unroll
          for (int j = 0; j < 4; ++j) {
            int k = kv0 + nh*16 + g*4 + j;
            pm[nh][j] = (k <= q) ? pm[nh][j] : -1e30f;
          }
      }

      // ---- in-lane row max + cross-group reduce
      float tm = -1e30f;
      #pragma unroll
      for (int nh = 0; nh < 4; ++nh)
        tm = fmaxf(tm, fmaxf(fmaxf(pm[nh][0], pm[nh][1]), fmaxf(pm[nh][2], pm[nh][3])));
      tm = fmaxf(tm, __shfl_xor(tm, 16, 64));
      tm = fmaxf(tm, __shfl_xor(tm, 32, 64));

      // ---- T13 defer-max (log2 domain; P bounded by 2^8)
      if (!__all(tm - mrun <= 8.f)) {
        float mnew = fmaxf(mrun, tm);
        float sc = exp2f(mrun - mnew);
        mrun = mnew;
        float scr[4];
        #pragma unroll
        for (int j = 0; j < 4; ++j) scr[j] = __shfl(sc, g*4 + j, 64);
        #pragma unroll
        for (int n2 = 0; n2 < 4; ++n2)
          #pragma unroll
          for (int j = 0; j < 4; ++j) o[n2][j] *= scr[j];
        lrun *= sc;
      }

      // ---- exp2, row-sum, pack P
      float ps = 0.f;
      #pragma unroll
      for (int nh = 0; nh < 4; ++nh) {
        #pragma unroll
        for (int j = 0; j < 4; ++j) { pm[nh][j] = exp2f(pm[nh][j] - mrun); ps += pm[nh][j]; }
        uint2 pk;
        pk.x = pkbf(pm[nh][0], pm[nh][1]);
        pk.y = pkbf(pm[nh][2], pm[nh][3]);
        *reinterpret_cast<uint2*>(Pw + poff[nh]) = pk;
      }
      ps += __shfl_xor(ps, 16, 64);
      ps += __shfl_xor(ps, 32, 64);
      lrun += ps;

      // ---- ensure P stores complete before P reads
      asm volatile("s_waitcnt lgkmcnt(0)" ::: "memory");
      __builtin_amdgcn_sched_barrier(0);

      // ---- PV
      __builtin_amdgcn_s_setprio(1);
      #pragma unroll
      for (int kk = 0; kk < 2; ++kk) {
        s16x8 pf = *reinterpret_cast<const s16x8*>(Pw + prd[kk]);
        #pragma unroll
        for (int n2 = 0; n2 < 4; ++n2) {
          s16x8 vf = *reinterpret_cast<const s16x8*>(&Vs[cur][voff[kk][n2]]);
          o[n2] = __builtin_amdgcn_mfma_f32_16x16x32_bf16(pf, vf, o[n2], 0, 0, 0);
        }
      }
      __builtin_amdgcn_s_setprio(0);
    }
    __syncthreads();   // drains vmcnt (prefetch) + all LDS reads of cur
  }

  if (nc == 1) {
    // single chunk: normalize and write bf16 directly
    float linv = 1.f / lrun;
    float lj[4];
    #pragma unroll
    for (int j = 0; j < 4; ++j) lj[j] = __shfl(linv, g*4 + j, 64);
    #pragma unroll
    for (int n2 = 0; n2 < 4; ++n2)
      #pragma unroll
      for (int j = 0; j < 4; ++j)
        out[(size_t)(b*S_ + q0w + g*4 + j)*E_ + h*64 + n2*16 + li] = f2bf(o[n2][j] * lj[j]);
  } else {
    // write partial: o bf16, m/l f32 (slot stride 2176 floats); m in log2-domain
    int cumP = (qt < 16) ? (qt-8)*2 : (qt < 24) ? 16 + (qt-16)*3 : 40 + (qt-24)*4;
    float* ps_ = part + (size_t)(bh*72 + cumP + ch) * 2176;
    unsigned short* ob = (unsigned short*)ps_;
    #pragma unroll
    for (int n2 = 0; n2 < 4; ++n2)
      #pragma unroll
      for (int j = 0; j < 4; ++j)
        ob[(w*16 + g*4 + j)*64 + n2*16 + li] = f2bf(o[n2][j]);
    if (g == 0) {
      ps_[2048 + w*16 + li] = mrun;
      ps_[2112 + w*16 + li] = lrun;
    }
  }
}

// ---------------- merge partial attention chunks (qt >= 8), bf16 partials,
// log2-domain m (exp2f weights)
__global__ __launch_bounds__(256) void merge_kernel(const float* __restrict__ part,
                                                    unsigned short* __restrict__ out) {
  int qt = 8 + blockIdx.x;
  int bh = blockIdx.y;
  int b = bh / H_, h = bh % H_;
  int t = threadIdx.x;
  int r = t >> 2, dg = (t & 3) * 16;
  int nc = (qt + 8) >> 3;
  int cumP = (qt < 16) ? (qt-8)*2 : (qt < 24) ? 16 + (qt-16)*3 : 40 + (qt-24)*4;
  const float* base = part + (size_t)(bh*72 + cumP) * 2176;

  float mv[4], lv[4];
  float M = -1e30f;
  for (int c = 0; c < nc; ++c) {
    mv[c] = base[c*2176 + 2048 + r];
    lv[c] = base[c*2176 + 2112 + r];
    M = fmaxf(M, mv[c]);
  }
  float wv[4], L = 0.f;
  for (int c = 0; c < nc; ++c) {
    wv[c] = exp2f(mv[c] - M);
    L += lv[c] * wv[c];
  }
  float inv = 1.f / L;
  float acc[16] = {};
  for (int c = 0; c < nc; ++c) {
    const unsigned short* ob = (const unsigned short*)(base + c*2176);
    const unsigned short* oc = ob + r*64 + dg;
    #pragma unroll
    for (int j = 0; j < 16; j += 4) {
      ushort4 v = *reinterpret_cast<const ushort4*>(oc + j);
      acc[j+0] += bf2f(v.x) * wv[c];
      acc[j+1] += bf2f(v.y) * wv[c];
      acc[j+2] += bf2f(v.z) * wv[c];
      acc[j+3] += bf2f(v.w) * wv[c];
    }
  }
  unsigned short* orow = out + (size_t)(b*S_ + qt*64 + r)*E_ + h*64 + dg;
  ushort4 o4;
  #pragma unroll
  for (int j = 0; j < 16; j += 4) {
    o4.x = f2bf(acc[j+0]*inv); o4.y = f2bf(acc[j+1]*inv);
    o4.z = f2bf(acc[j+2]*inv); o4.w = f2bf(acc[j+3]*inv);
    *reinterpret_cast<ushort4*>(orow + j) = o4;
  }
}

extern "C" void kernel_launch(void* const* d_in, const int* in_sizes, int n_in,
                              void* d_out, int out_size, void* d_ws, size_t ws_size,
                              hipStream_t stream) {
  const float* x       = (const float*)d_in[0];
  const float* ln1g    = (const float*)d_in[1];
  const float* ln1b    = (const float*)d_in[2];
  const float* w_attn  = (const float*)d_in[3];
  const float* b_attn  = (const float*)d_in[4];
  const float* w_aproj = (const float*)d_in[5];
  const float* b_aproj = (const float*)d_in[6];
  const float* ln2g    = (const float*)d_in[7];
  const float* ln2b    = (const float*)d_in[8];
  const float* w_fc    = (const float*)d_in[9];
  const float* b_fc    = (const float*)d_in[10];
  const float* w_fproj = (const float*)d_in[11];
  const float* b_fproj = (const float*)d_in[12];
  float* out = (float*)d_out;

  char* ws = (char*)d_ws;
  unsigned short* h1       = (unsigned short*)(ws + 0);          // 4096x768 bf16
  unsigned short* qkv      = (unsigned short*)(ws + 6291456);    // 4096x2304 bf16
  unsigned short* attno    = (unsigned short*)(ws + 25165824);   // 4096x768 bf16
  float*          x2       = (float*)(ws + 31457280);            // 4096x768 f32
  unsigned short* h2       = (unsigned short*)(ws + 44040192);   // 4096x768 bf16
  unsigned short* h3       = (unsigned short*)(ws + 50331648);   // 4096x3072 bf16
  unsigned short* wt_attn  = (unsigned short*)(ws + 75497472);   // 2304x768 bf16
  unsigned short* wt_aproj = (unsigned short*)(ws + 79036416);   // 768x768
  unsigned short* wt_fc    = (unsigned short*)(ws + 80216064);   // 3072x768
  unsigned short* wt_fproj = (unsigned short*)(ws + 84934656);   // 768x3072
  unsigned short* vtg      = (unsigned short*)(ws + 89653248);   // 1536x2048 bf16 (V^T)
  float*          apart    = (float*)(ws + 44040192);            // attn partials 15MB (overlaps h2/h3; dead before h2/h3 written)

  // fused weight transposes + LN1
  prep_kernel<<<dim3(7936), 256, 0, stream>>>(w_attn, wt_attn, w_aproj, wt_aproj,
                                              w_fc, wt_fc, w_fproj, wt_fproj,
                                              x, ln1g, ln1b, h1);
  // QKV: BM=64 BK=128, grid (18, 64)
  gemm_kernel<0,64><<<dim3(2304/128, M_TOT/64), 256, 0, stream>>>(h1, wt_attn, b_attn, nullptr, qkv, nullptr, M_TOT, 2304, 768);
  // V transpose for attention
  vtrans_kernel<<<dim3(S_/32, B_*H_*2), 256, 0, stream>>>(qkv, vtg);
  // attention: KV-split (8 xcd x 3 bh x 80 (qt,chunk)) + merge
  attn_kernel<<<dim3(24*80), dim3(256), 0, stream>>>(qkv, vtg, attno, apart);
  merge_kernel<<<dim3(24, 24), dim3(256), 0, stream>>>(apart, attno);
  // attn proj + residual -> x2 (f32): grid (6, 64)
  gemm_kernel<1,64><<<dim3(768/128, M_TOT/64), 256, 0, stream>>>(attno, wt_aproj, b_aproj, x, nullptr, x2, M_TOT, 768, 768);
  // LN2 (4 rows/block)
  ln_kernel<<<dim3(M_TOT/4), 256, 0, stream>>>(x2, ln2g, ln2b, h2);
  // FC + gelu: grid (24, 64)
  gemm_kernel<2,64><<<dim3(3072/128, M_TOT/64), 256, 0, stream>>>(h2, wt_fc, b_fc, nullptr, h3, nullptr, M_TOT, 3072, 768);
  // fproj + residual -> out (f32): grid (6, 64), KT=24
  gemm_kernel<1,64><<<dim3(768/128, M_TOT/64), 256, 0, stream>>>(h3, wt_fproj, b_fproj, x2, nullptr, out, M_TOT, 768, 3072);
}

// Round 17
// 175.695 us; speedup vs baseline: 1.0424x; 1.0424x over previous
//
#include <hip/hip_runtime.h>
#include <hip/hip_bf16.h>
#include <math.h>

#define B_ 2
#define S_ 2048
#define E_ 768
#define H_ 12
#define D_ 64
#define M_TOT (B_*S_)   // 4096

typedef __attribute__((ext_vector_type(8))) short s16x8;
typedef __attribute__((ext_vector_type(4))) float f32x4;

__device__ __forceinline__ unsigned short f2bf(float f) {
  union { float f; unsigned u; } v; v.f = f;
  unsigned r = (v.u + 0x7fffu + ((v.u >> 16) & 1u)) >> 16;
  return (unsigned short)r;
}

__device__ __forceinline__ unsigned pkbf(float a, float b) {
  __hip_bfloat162 h = __float22bfloat162_rn(make_float2(a, b));
  unsigned u;
  __builtin_memcpy(&u, &h, 4);
  return u;
}

__device__ __forceinline__ float bf2f(unsigned short u) {
  union { unsigned u; float f; } v; v.u = (unsigned)u << 16;
  return v.f;
}

__device__ __forceinline__ float fexp2(float x) {   // raw v_exp_f32: D = 2^S0
  return __builtin_amdgcn_exp2f(x);
}

__device__ __forceinline__ int swz(int r) { return ((r >> 3) ^ r) & 7; }

__device__ __forceinline__ void gload_lds16(const unsigned short* g, unsigned short* l) {
  __builtin_amdgcn_global_load_lds(
      (const __attribute__((address_space(1))) void*)g,
      (__attribute__((address_space(3))) void*)l, 16, 0, 0);
}

// ---------------- transpose+convert block: in [R][C] f32 -> out [C][R] bf16
__device__ __forceinline__ void tconv_block(const float* __restrict__ in,
                                            unsigned short* __restrict__ out,
                                            int R, int C, int bx, int by, int t,
                                            float (*tile)[33]) {
  int c0 = bx * 32, r0 = by * 32;
  int cl = t & 31, rl = t >> 5;
  #pragma unroll
  for (int p = 0; p < 4; ++p)
    tile[rl + p*8][cl] = in[(size_t)(r0 + rl + p*8)*C + c0 + cl];
  __syncthreads();
  int rl2 = t & 31, cl2 = t >> 5;
  #pragma unroll
  for (int p = 0; p < 4; ++p)
    out[(size_t)(c0 + cl2 + p*8)*R + r0 + rl2] = f2bf(tile[rl2][cl2 + p*8]);
}

// ---------------- layernorm one row (wave of 64 lanes, no barriers)
__device__ __forceinline__ void ln_row(const float* __restrict__ xr,
                                       const float* __restrict__ g,
                                       const float* __restrict__ b,
                                       unsigned short* __restrict__ orow, int lane) {
  float4 v[3];
  float s = 0.f, sq = 0.f;
  #pragma unroll
  for (int p = 0; p < 3; ++p) {
    v[p] = *reinterpret_cast<const float4*>(xr + p*256 + lane*4);
    s  += v[p].x + v[p].y + v[p].z + v[p].w;
    sq += v[p].x*v[p].x + v[p].y*v[p].y + v[p].z*v[p].z + v[p].w*v[p].w;
  }
  #pragma unroll
  for (int off = 32; off; off >>= 1) {
    s  += __shfl_xor(s,  off, 64);
    sq += __shfl_xor(sq, off, 64);
  }
  float mu  = s * (1.f/E_);
  float var = sq * (1.f/E_) - mu*mu;
  float rstd = rsqrtf(var + 1e-5f);
  #pragma unroll
  for (int p = 0; p < 3; ++p) {
    int c = p*256 + lane*4;
    float4 gg = *reinterpret_cast<const float4*>(g + c);
    float4 bb = *reinterpret_cast<const float4*>(b + c);
    ushort4 o;
    o.x = f2bf((v[p].x-mu)*rstd*gg.x + bb.x);
    o.y = f2bf((v[p].y-mu)*rstd*gg.y + bb.y);
    o.z = f2bf((v[p].z-mu)*rstd*gg.z + bb.z);
    o.w = f2bf((v[p].w-mu)*rstd*gg.w + bb.w);
    *reinterpret_cast<ushort4*>(orow + c) = o;
  }
}

// ---------------- mega-prep: 4 weight tconvs + LN1, one kernel (flat decode)
__global__ __launch_bounds__(256) void prep_kernel(
    const float* __restrict__ w_attn,  unsigned short* __restrict__ wt_attn,
    const float* __restrict__ w_aproj, unsigned short* __restrict__ wt_aproj,
    const float* __restrict__ w_fc,    unsigned short* __restrict__ wt_fc,
    const float* __restrict__ w_fproj, unsigned short* __restrict__ wt_fproj,
    const float* __restrict__ x, const float* __restrict__ ln1g,
    const float* __restrict__ ln1b, unsigned short* __restrict__ h1) {
  __shared__ float tile[32][33];
  int id = blockIdx.x, t = threadIdx.x;
  if (id < 1728) {
    tconv_block(w_attn, wt_attn, 768, 2304, id % 72, id / 72, t, tile);
  } else if (id < 2304) {
    int r = id - 1728; tconv_block(w_aproj, wt_aproj, 768, 768, r % 24, r / 24, t, tile);
  } else if (id < 4608) {
    int r = id - 2304; tconv_block(w_fc, wt_fc, 768, 3072, r % 96, r / 96, t, tile);
  } else if (id < 6912) {
    int r = id - 4608; tconv_block(w_fproj, wt_fproj, 3072, 768, r % 24, r / 24, t, tile);
  } else {
    int row = (id - 6912) * 4 + (t >> 6);
    ln_row(x + (size_t)row * E_, ln1g, ln1b, h1 + (size_t)row * E_, t & 63);
  }
}

// ---------------- layernorm (4 rows/block): x f32 [rows][768] -> out bf16
__global__ __launch_bounds__(256) void ln_kernel(const float* __restrict__ x,
                                                 const float* __restrict__ g,
                                                 const float* __restrict__ b,
                                                 unsigned short* __restrict__ out) {
  int row = blockIdx.x * 4 + (threadIdx.x >> 6);
  ln_row(x + (size_t)row * E_, g, b, out + (size_t)row * E_, threadIdx.x & 63);
}

// ---------------- V transpose: qkv bf16 [B*S][2304] -> vt [ (b*H+h)*64+d ][ S ] bf16
__global__ __launch_bounds__(256) void vtrans_kernel(const unsigned short* __restrict__ qkv,
                                                     unsigned short* __restrict__ vt) {
  __shared__ unsigned short tile[32][33];
  int s0 = blockIdx.x * 32;
  int by = blockIdx.y;                // bh*2 + d-half
  int bh = by >> 1, dh = by & 1;
  int b = bh / H_, h = bh % H_;
  int t = threadIdx.x;
  const unsigned short* src = qkv + (size_t)(b*S_)*2304 + 2*E_ + h*64 + dh*32;
  int srow = t >> 3, dq = t & 7;      // load: 32 s-rows x 32 d
  ushort4 v = *reinterpret_cast<const ushort4*>(src + (size_t)(s0 + srow)*2304 + dq*4);
  tile[srow][dq*4+0] = v.x; tile[srow][dq*4+1] = v.y;
  tile[srow][dq*4+2] = v.z; tile[srow][dq*4+3] = v.w;
  __syncthreads();
  int drow = t >> 3, sq = t & 7;      // store: 32 d-rows x 32 s
  ushort4 o;
  o.x = tile[sq*4+0][drow]; o.y = tile[sq*4+1][drow];
  o.z = tile[sq*4+2][drow]; o.w = tile[sq*4+3][drow];
  *reinterpret_cast<ushort4*>(vt + (size_t)(bh*64 + dh*32 + drow)*S_ + s0 + sq*4) = o;
}

// ---------------- GEMM v6: BK=128, BM=64, BN=128, single-buffered LDS,
// XCD-aware block remap: each XCD owns a contiguous m-chunk, n-fastest within.
// MODE 0: store bf16 ; MODE 1: store f32 + residual ; MODE 2: gelu -> bf16
template<int MODE, int BM>
__global__ __launch_bounds__(256) void gemm_kernel(
    const unsigned short* __restrict__ A,
    const unsigned short* __restrict__ Wt,
    const float* __restrict__ bias,
    const float* __restrict__ res,
    unsigned short* __restrict__ outb,
    float* __restrict__ outf,
    int M, int N, int K)
{
  constexpr int Mi = BM / 32;
  constexpr int Ni = 4;
  __shared__ __align__(16) unsigned short As[BM*128];
  __shared__ __align__(16) unsigned short Ws[128*128];

  int gx = gridDim.x, gy = gridDim.y;
  int bid = blockIdx.y * gx + blockIdx.x;
  int xcd = bid & 7, loc = bid >> 3;
  int m = xcd * (gy >> 3) + loc / gx;
  int n = loc % gx;
  int n0 = n * 128, m0 = m * BM;

  int t = threadIdx.x, lane = t & 63, w = t >> 6;
  f32x4 acc[Mi][Ni] = {};
  int KT = K >> 7;

  auto stage = [&](int kt) {
    int k0 = kt << 7;
    #pragma unroll
    for (int p = 0; p < BM/16; ++p) {
      int off = p*2048 + w*512 + lane*8;
      int r = off >> 7;
      int slot = (off & 127) >> 3;
      int k8 = slot ^ swz(r);
      gload_lds16(A + (size_t)(m0 + r)*K + k0 + k8*8, As + p*2048 + w*512);
    }
    #pragma unroll
    for (int p = 0; p < 8; ++p) {
      int off = p*2048 + w*512 + lane*8;
      int r = off >> 7;
      int slot = (off & 127) >> 3;
      int k8 = slot ^ swz(r);
      gload_lds16(Wt + (size_t)(n0 + r)*K + k0 + k8*8, Ws + p*2048 + w*512);
    }
  };

  int wm = (w >> 1) * (BM/2), wn = (w & 1) * 64;
  int li = lane & 15, g = lane >> 4;

  int aoff[Mi], boff[Ni];
  #pragma unroll
  for (int mi = 0; mi < Mi; ++mi) {
    int r = wm + mi*16 + li;
    aoff[mi] = r*128 + ((g ^ swz(r)) << 3);
  }
  #pragma unroll
  for (int ni = 0; ni < Ni; ++ni) {
    int r = wn + ni*16 + li;
    boff[ni] = r*128 + ((g ^ swz(r)) << 3);
  }

  stage(0);
  for (int kt = 0; kt < KT; ++kt) {
    __syncthreads();
    #pragma unroll
    for (int kk = 0; kk < 4; ++kk) {
      int kx = kk << 5;
      s16x8 af[Mi], bf[Ni];
      #pragma unroll
      for (int mi = 0; mi < Mi; ++mi)
        af[mi] = *reinterpret_cast<const s16x8*>(As + (aoff[mi] ^ kx));
      #pragma unroll
      for (int ni = 0; ni < Ni; ++ni)
        bf[ni] = *reinterpret_cast<const s16x8*>(Ws + (boff[ni] ^ kx));
      #pragma unroll
      for (int mi = 0; mi < Mi; ++mi)
        #pragma unroll
        for (int ni = 0; ni < Ni; ++ni)
          acc[mi][ni] = __builtin_amdgcn_mfma_f32_16x16x32_bf16(af[mi], bf[ni], acc[mi][ni], 0, 0, 0);
    }
    __syncthreads();
    if (kt + 1 < KT) stage(kt + 1);
  }

  #pragma unroll
  for (int mi = 0; mi < Mi; ++mi) {
    #pragma unroll
    for (int j = 0; j < 4; ++j) {
      int row = m0 + wm + mi*16 + g*4 + j;
      #pragma unroll
      for (int ni = 0; ni < Ni; ++ni) {
        int col = n0 + wn + ni*16 + li;
        float v = acc[mi][ni][j] + bias[col];
        size_t idx = (size_t)row * N + col;
        if (MODE == 0) {
          outb[idx] = f2bf(v);
        } else if (MODE == 1) {
          outf[idx] = v + res[idx];
        } else {
          float gv = 0.5f * v * (1.f + erff(v * 0.70710678118f));
          outb[idx] = f2bf(gv);
        }
      }
    }
  }
}

// ---------------- causal flash attention v12: v11 with raw v_exp_f32
// (__builtin_amdgcn_exp2f) instead of libm exp2f. Q pre-scaled by log2(e);
// m/l in log2-domain; bh-per-XCD remap; defer-max; bf16 partials.
// Block = (bh, qtile of 64 rows, kv chunk of <=512). 4 waves, wave owns 16 q rows.
// Partial slot (floats, stride 2176): o bf16[64][64] @0, m[64] @2048, l[64] @2112.
__global__ __launch_bounds__(256) void attn_kernel(const unsigned short* __restrict__ qkv,
                                                   const unsigned short* __restrict__ vtg,
                                                   unsigned short* __restrict__ out,
                                                   float* __restrict__ part) {
  __shared__ __align__(16) unsigned short Ks[2][64*64];   // [kv][d] swizzled
  __shared__ __align__(16) unsigned short Vs[2][64*64];   // [d][kv] swizzled
  __shared__ __align__(16) unsigned short Pl[4][16*64];   // per-wave P [16q][64k] swizzled

  // ---- XCD-aware decode: grid 1920 = 8 xcd x 240; each XCD owns 3 bh
  int gid = blockIdx.x;
  int xcd = gid & 7, loc = gid >> 3;           // loc in [0,240)
  int bh = xcd * 3 + loc / 80, zi = loc % 80;
  int qt, ch;
  if (zi < 8)       { qt = zi;                ch = 0; }
  else if (zi < 24) { qt = 8  + ((zi-8)>>1);  ch = (zi-8) & 1; }
  else if (zi < 48) { qt = 16 + (zi-24)/3;    ch = (zi-24) % 3; }
  else              { qt = 24 + ((zi-48)>>2); ch = (zi-48) & 3; }
  int nc = (qt + 8) >> 3;                      // ceil((qt+1)/8)
  int b = bh / H_, h = bh % H_;
  int t = threadIdx.x, lane = t & 63, w = t >> 6;
  int li = lane & 15, g = lane >> 4;
  const size_t rs = 3*E_;                      // 2304
  const unsigned short* base  = qkv + (size_t)b * S_ * rs;
  const unsigned short* kbase = base + E_ + h*64;
  const unsigned short* vbase = vtg + (size_t)bh * 64 * S_;   // rows d, cols s

  int q0w = qt*64 + w*16;                      // this wave's 16 q rows
  int qmin = q0w;
  s16x8 qf[2];
  #pragma unroll
  for (int f = 0; f < 2; ++f)
    qf[f] = *reinterpret_cast<const s16x8*>(base + (size_t)(q0w + li)*rs + h*64 + f*32 + g*8);
  // pre-scale Q by log2(e): scores come out of MFMA already in log2 domain
  #pragma unroll
  for (int f = 0; f < 2; ++f)
    #pragma unroll
    for (int i = 0; i < 8; ++i)
      qf[f][i] = (short)f2bf(bf2f((unsigned short)qf[f][i]) * 1.44269504f);

  // ---- hoisted LDS offsets (loop-invariant)
  int koff0[4], koff1[4], poff[4], prd[2], voff[2][4];
  #pragma unroll
  for (int nh = 0; nh < 4; ++nh) {
    int r = nh*16 + li, sw_ = r & 7;
    koff0[nh] = r*64 + ((g ^ sw_) << 3);
    koff1[nh] = r*64 + (((4 + g) ^ sw_) << 3);
    poff[nh]  = li*64 + (((2*nh + (g >> 1)) ^ (li & 7)) << 3) + (g & 1)*4;
  }
  #pragma unroll
  for (int kk = 0; kk < 2; ++kk) {
    prd[kk] = li*64 + (((kk*4 + g) ^ (li & 7)) << 3);
    #pragma unroll
    for (int n2 = 0; n2 < 4; ++n2) {
      int r = n2*16 + li;
      voff[kk][n2] = r*64 + (((kk*4 + g) ^ (r & 7)) << 3);
    }
  }

  float mrun = -1e30f, lrun = 0.f;
  f32x4 o[4] = {};

  auto stage = [&](int kvt, int buf) {
    int kv0 = kvt * 64;
    #pragma unroll
    for (int p = 0; p < 2; ++p) {
      int off = p*2048 + w*512 + lane*8;
      int r = off >> 6;
      int slot = (off & 63) >> 3;
      gload_lds16(kbase + (size_t)(kv0 + r)*rs + ((slot ^ (r & 7)) << 3),
                  &Ks[buf][p*2048 + w*512]);
      gload_lds16(vbase + (size_t)r*S_ + kv0 + ((slot ^ (r & 7)) << 3),
                  &Vs[buf][p*2048 + w*512]);
    }
  };

  int t0 = (ch * 512) >> 6;
  int t1 = min((ch + 1) * 512, (qt + 1) * 64) >> 6;   // exclusive tile bound

  stage(t0, 0);
  __syncthreads();

  for (int kt = t0; kt < t1; ++kt) {
    int cur = (kt - t0) & 1;
    if (kt + 1 < t1) stage(kt + 1, cur ^ 1);   // async prefetch overlaps compute
    int kv0 = kt * 64;
    unsigned short* Pw = Pl[w];

    if (kv0 <= qmin + 15) {
      // ---- swapped QK^T (log2-domain scores)
      f32x4 pm[4];
      __builtin_amdgcn_s_setprio(1);
      #pragma unroll
      for (int nh = 0; nh < 4; ++nh) {
        s16x8 kf0 = *reinterpret_cast<const s16x8*>(&Ks[cur][koff0[nh]]);
        s16x8 kf1 = *reinterpret_cast<const s16x8*>(&Ks[cur][koff1[nh]]);
        f32x4 z = {};
        z = __builtin_amdgcn_mfma_f32_16x16x32_bf16(kf0, qf[0], z, 0, 0, 0);
        z = __builtin_amdgcn_mfma_f32_16x16x32_bf16(kf1, qf[1], z, 0, 0, 0);
        pm[nh] = z;
      }
      __builtin_amdgcn_s_setprio(0);

      // ---- causal mask (diagonal-straddling tiles only)
      if (kv0 + 63 > qmin) {
        int q = qmin + li;
        #pragma unroll
        for (int nh = 0; nh < 4; ++nh)
          #pragma unroll
          for (int j = 0; j < 4; ++j) {
            int k = kv0 + nh*16 + g*4 + j;
            pm[nh][j] = (k <= q) ? pm[nh][j] : -1e30f;
          }
      }

      // ---- in-lane row max + cross-group reduce
      float tm = -1e30f;
      #pragma unroll
      for (int nh = 0; nh < 4; ++nh)
        tm = fmaxf(tm, fmaxf(fmaxf(pm[nh][0], pm[nh][1]), fmaxf(pm[nh][2], pm[nh][3])));
      tm = fmaxf(tm, __shfl_xor(tm, 16, 64));
      tm = fmaxf(tm, __shfl_xor(tm, 32, 64));

      // ---- T13 defer-max (log2 domain; P bounded by 2^8)
      if (!__all(tm - mrun <= 8.f)) {
        float mnew = fmaxf(mrun, tm);
        float sc = fexp2(mrun - mnew);
        mrun = mnew;
        float scr[4];
        #pragma unroll
        for (int j = 0; j < 4; ++j) scr[j] = __shfl(sc, g*4 + j, 64);
        #pragma unroll
        for (int n2 = 0; n2 < 4; ++n2)
          #pragma unroll
          for (int j = 0; j < 4; ++j) o[n2][j] *= scr[j];
        lrun *= sc;
      }

      // ---- exp2 (raw v_exp_f32), row-sum, pack P
      float ps = 0.f;
      #pragma unroll
      for (int nh = 0; nh < 4; ++nh) {
        #pragma unroll
        for (int j = 0; j < 4; ++j) { pm[nh][j] = fexp2(pm[nh][j] - mrun); ps += pm[nh][j]; }
        uint2 pk;
        pk.x = pkbf(pm[nh][0], pm[nh][1]);
        pk.y = pkbf(pm[nh][2], pm[nh][3]);
        *reinterpret_cast<uint2*>(Pw + poff[nh]) = pk;
      }
      ps += __shfl_xor(ps, 16, 64);
      ps += __shfl_xor(ps, 32, 64);
      lrun += ps;

      // ---- ensure P stores complete before P reads
      asm volatile("s_waitcnt lgkmcnt(0)" ::: "memory");
      __builtin_amdgcn_sched_barrier(0);

      // ---- PV
      __builtin_amdgcn_s_setprio(1);
      #pragma unroll
      for (int kk = 0; kk < 2; ++kk) {
        s16x8 pf = *reinterpret_cast<const s16x8*>(Pw + prd[kk]);
        #pragma unroll
        for (int n2 = 0; n2 < 4; ++n2) {
          s16x8 vf = *reinterpret_cast<const s16x8*>(&Vs[cur][voff[kk][n2]]);
          o[n2] = __builtin_amdgcn_mfma_f32_16x16x32_bf16(pf, vf, o[n2], 0, 0, 0);
        }
      }
      __builtin_amdgcn_s_setprio(0);
    }
    __syncthreads();   // drains vmcnt (prefetch) + all LDS reads of cur
  }

  if (nc == 1) {
    // single chunk: normalize and write bf16 directly
    float linv = 1.f / lrun;
    float lj[4];
    #pragma unroll
    for (int j = 0; j < 4; ++j) lj[j] = __shfl(linv, g*4 + j, 64);
    #pragma unroll
    for (int n2 = 0; n2 < 4; ++n2)
      #pragma unroll
      for (int j = 0; j < 4; ++j)
        out[(size_t)(b*S_ + q0w + g*4 + j)*E_ + h*64 + n2*16 + li] = f2bf(o[n2][j] * lj[j]);
  } else {
    // write partial: o bf16, m/l f32 (slot stride 2176 floats); m in log2-domain
    int cumP = (qt < 16) ? (qt-8)*2 : (qt < 24) ? 16 + (qt-16)*3 : 40 + (qt-24)*4;
    float* ps_ = part + (size_t)(bh*72 + cumP + ch) * 2176;
    unsigned short* ob = (unsigned short*)ps_;
    #pragma unroll
    for (int n2 = 0; n2 < 4; ++n2)
      #pragma unroll
      for (int j = 0; j < 4; ++j)
        ob[(w*16 + g*4 + j)*64 + n2*16 + li] = f2bf(o[n2][j]);
    if (g == 0) {
      ps_[2048 + w*16 + li] = mrun;
      ps_[2112 + w*16 + li] = lrun;
    }
  }
}

// ---------------- merge partial attention chunks (qt >= 8), bf16 partials,
// log2-domain m (v_exp_f32 weights)
__global__ __launch_bounds__(256) void merge_kernel(const float* __restrict__ part,
                                                    unsigned short* __restrict__ out) {
  int qt = 8 + blockIdx.x;
  int bh = blockIdx.y;
  int b = bh / H_, h = bh % H_;
  int t = threadIdx.x;
  int r = t >> 2, dg = (t & 3) * 16;
  int nc = (qt + 8) >> 3;
  int cumP = (qt < 16) ? (qt-8)*2 : (qt < 24) ? 16 + (qt-16)*3 : 40 + (qt-24)*4;
  const float* base = part + (size_t)(bh*72 + cumP) * 2176;

  float mv[4], lv[4];
  float M = -1e30f;
  for (int c = 0; c < nc; ++c) {
    mv[c] = base[c*2176 + 2048 + r];
    lv[c] = base[c*2176 + 2112 + r];
    M = fmaxf(M, mv[c]);
  }
  float wv[4], L = 0.f;
  for (int c = 0; c < nc; ++c) {
    wv[c] = __builtin_amdgcn_exp2f(mv[c] - M);
    L += lv[c] * wv[c];
  }
  float inv = 1.f / L;
  float acc[16] = {};
  for (int c = 0; c < nc; ++c) {
    const unsigned short* ob = (const unsigned short*)(base + c*2176);
    const unsigned short* oc = ob + r*64 + dg;
    #pragma unroll
    for (int j = 0; j < 16; j += 4) {
      ushort4 v = *reinterpret_cast<const ushort4*>(oc + j);
      acc[j+0] += bf2f(v.x) * wv[c];
      acc[j+1] += bf2f(v.y) * wv[c];
      acc[j+2] += bf2f(v.z) * wv[c];
      acc[j+3] += bf2f(v.w) * wv[c];
    }
  }
  unsigned short* orow = out + (size_t)(b*S_ + qt*64 + r)*E_ + h*64 + dg;
  ushort4 o4;
  #pragma unroll
  for (int j = 0; j < 16; j += 4) {
    o4.x = f2bf(acc[j+0]*inv); o4.y = f2bf(acc[j+1]*inv);
    o4.z = f2bf(acc[j+2]*inv); o4.w = f2bf(acc[j+3]*inv);
    *reinterpret_cast<ushort4*>(orow + j) = o4;
  }
}

extern "C" void kernel_launch(void* const* d_in, const int* in_sizes, int n_in,
                              void* d_out, int out_size, void* d_ws, size_t ws_size,
                              hipStream_t stream) {
  const float* x       = (const float*)d_in[0];
  const float* ln1g    = (const float*)d_in[1];
  const float* ln1b    = (const float*)d_in[2];
  const float* w_attn  = (const float*)d_in[3];
  const float* b_attn  = (const float*)d_in[4];
  const float* w_aproj = (const float*)d_in[5];
  const float* b_aproj = (const float*)d_in[6];
  const float* ln2g    = (const float*)d_in[7];
  const float* ln2b    = (const float*)d_in[8];
  const float* w_fc    = (const float*)d_in[9];
  const float* b_fc    = (const float*)d_in[10];
  const float* w_fproj = (const float*)d_in[11];
  const float* b_fproj = (const float*)d_in[12];
  float* out = (float*)d_out;

  char* ws = (char*)d_ws;
  unsigned short* h1       = (unsigned short*)(ws + 0);          // 4096x768 bf16
  unsigned short* qkv      = (unsigned short*)(ws + 6291456);    // 4096x2304 bf16
  unsigned short* attno    = (unsigned short*)(ws + 25165824);   // 4096x768 bf16
  float*          x2       = (float*)(ws + 31457280);            // 4096x768 f32
  unsigned short* h2       = (unsigned short*)(ws + 44040192);   // 4096x768 bf16
  unsigned short* h3       = (unsigned short*)(ws + 50331648);   // 4096x3072 bf16
  unsigned short* wt_attn  = (unsigned short*)(ws + 75497472);   // 2304x768 bf16
  unsigned short* wt_aproj = (unsigned short*)(ws + 79036416);   // 768x768
  unsigned short* wt_fc    = (unsigned short*)(ws + 80216064);   // 3072x768
  unsigned short* wt_fproj = (unsigned short*)(ws + 84934656);   // 768x3072
  unsigned short* vtg      = (unsigned short*)(ws + 89653248);   // 1536x2048 bf16 (V^T)
  float*          apart    = (float*)(ws + 44040192);            // attn partials 15MB (overlaps h2/h3; dead before h2/h3 written)

  // fused weight transposes + LN1
  prep_kernel<<<dim3(7936), 256, 0, stream>>>(w_attn, wt_attn, w_aproj, wt_aproj,
                                              w_fc, wt_fc, w_fproj, wt_fproj,
                                              x, ln1g, ln1b, h1);
  // QKV: BM=64 BK=128, grid (18, 64)
  gemm_kernel<0,64><<<dim3(2304/128, M_TOT/64), 256, 0, stream>>>(h1, wt_attn, b_attn, nullptr, qkv, nullptr, M_TOT, 2304, 768);
  // V transpose for attention
  vtrans_kernel<<<dim3(S_/32, B_*H_*2), 256, 0, stream>>>(qkv, vtg);
  // attention: KV-split (8 xcd x 3 bh x 80 (qt,chunk)) + merge
  attn_kernel<<<dim3(24*80), dim3(256), 0, stream>>>(qkv, vtg, attno, apart);
  merge_kernel<<<dim3(24, 24), dim3(256), 0, stream>>>(apart, attno);
  // attn proj + residual -> x2 (f32): grid (6, 64)
  gemm_kernel<1,64><<<dim3(768/128, M_TOT/64), 256, 0, stream>>>(attno, wt_aproj, b_aproj, x, nullptr, x2, M_TOT, 768, 768);
  // LN2 (4 rows/block)
  ln_kernel<<<dim3(M_TOT/4), 256, 0, stream>>>(x2, ln2g, ln2b, h2);
  // FC + gelu: grid (24, 64)
  gemm_kernel<2,64><<<dim3(3072/128, M_TOT/64), 256, 0, stream>>>(h2, wt_fc, b_fc, nullptr, h3, nullptr, M_TOT, 3072, 768);
  // fproj + residual -> out (f32): grid (6, 64), KT=24
  gemm_kernel<1,64><<<dim3(768/128, M_TOT/64), 256, 0, stream>>>(h3, wt_fproj, b_fproj, x2, nullptr, out, M_TOT, 768, 3072);
}